// Round 4
// baseline (167.533 us; speedup 1.0000x reference)
//
#include <hip/hip_runtime.h>
#include <hip/hip_bf16.h>

// NormPool2d: 3x3 reflect-padded window, output = mean - unbiased std.
// x: (16, 96, 224, 224) fp32 -> out same shape, fp32.
//
// Round 4: rounds 1-3 all land ~147-156us at ~3.3 TB/s. Occupancy-tail
// analysis shows time scales with per-thread sequential row count, not with
// resident work -> latency-serial, compiler refuses to pipeline (VGPR=36).
// Structural fix:
//  - TWO independent plane streams per thread (plane p and p+768): their
//    loads are consumed in the same iteration and cannot be serialized ->
//    2x in-flight loads per wave, guaranteed.
//  - CHUNKS 16 (14 rows/thread): sequential latency chain halves vs round 3.
//  - Depth-1 raw prefetch per stream retained (load h+2 while emitting h).
// Cost: chunk overlap reads 16/14 = +14%.

#define NP_W 224
#define NP_H 224
#define NP_PH 768            // plane pairs: (p, p+768), 1536 planes total
#define NP_STRIPS (NP_W / 4) // 56
#define NP_CHUNKS 16
#define NP_CROWS (NP_H / NP_CHUNKS)  // 14

struct Raw { float4 v; float lf, rt; };

__device__ __forceinline__ Raw load_row(const float* __restrict__ xp, int h,
                                        int w, bool le, bool re) {
    Raw r;
    const float* row = xp + (size_t)h * NP_W;
    r.v = *reinterpret_cast<const float4*>(row + w);
    r.lf = le ? r.v.y : row[w - 1];   // reflect: x[-1] -> x[1]
    r.rt = re ? r.v.z : row[w + 4];   // reflect: x[W] -> x[W-2]
    return r;
}

__device__ __forceinline__ void row_sums(const Raw& r, float4& rs, float4& rq) {
    rs.x = r.lf + r.v.x + r.v.y;
    rs.y = r.v.x + r.v.y + r.v.z;
    rs.z = r.v.y + r.v.z + r.v.w;
    rs.w = r.v.z + r.v.w + r.rt;
    float l2 = r.lf * r.lf, a2 = r.v.x * r.v.x, b2 = r.v.y * r.v.y;
    float c2 = r.v.z * r.v.z, d2 = r.v.w * r.v.w, r2 = r.rt * r.rt;
    rq.x = l2 + a2 + b2;
    rq.y = a2 + b2 + c2;
    rq.z = b2 + c2 + d2;
    rq.w = c2 + d2 + r2;
}

__device__ __forceinline__ float finish1(float s, float q) {
    float mean = s * (1.f / 9.f);
    float var = (q - s * mean) * 0.125f;  // unbiased: (ss - s^2/9)/8
    return mean - sqrtf(fmaxf(var, 0.f));
}

__device__ __forceinline__ void emit_row(float* __restrict__ op, int h,
                                         const float4& s0, const float4& s1,
                                         const float4& s2, const float4& q0,
                                         const float4& q1, const float4& q2) {
    float4 o;
    o.x = finish1(s0.x + s1.x + s2.x, q0.x + q1.x + q2.x);
    o.y = finish1(s0.y + s1.y + s2.y, q0.y + q1.y + q2.y);
    o.z = finish1(s0.z + s1.z + s2.z, q0.z + q1.z + q2.z);
    o.w = finish1(s0.w + s1.w + s2.w, q0.w + q1.w + q2.w);
    *reinterpret_cast<float4*>(op + (size_t)h * NP_W) = o;
}

__global__ __launch_bounds__(256) void NormPool2d_kernel(
    const float* __restrict__ x, float* __restrict__ out) {
    const int W = NP_W, H = NP_H;
    int f = blockIdx.x * blockDim.x + threadIdx.x;
    int strip = f % NP_STRIPS;
    int t = f / NP_STRIPS;
    int chunk = t % NP_CHUNKS;
    int ph = t / NP_CHUNKS;   // [0, 768)
    int w = strip * 4;

    const bool le = (w == 0);
    const bool re = (w == W - 4);

    const float* __restrict__ xa = x + (size_t)ph * (H * W);
    const float* __restrict__ xb = x + (size_t)(ph + NP_PH) * (H * W);
    float* __restrict__ oa = out + (size_t)ph * (H * W) + w;
    float* __restrict__ ob = out + (size_t)(ph + NP_PH) * (H * W) + w;

    int r0 = chunk * NP_CROWS;
    int r1 = r0 + NP_CROWS;
    int hm = (r0 == 0) ? 1 : r0 - 1;  // reflect: row -1 -> row 1

    // Prologue: issue all 6 row-loads (3 per stream) before any consumption.
    Raw pA = load_row(xa, hm, w, le, re);
    Raw pB = load_row(xb, hm, w, le, re);
    Raw cA = load_row(xa, r0, w, le, re);
    Raw cB = load_row(xb, r0, w, le, re);
    Raw nA = load_row(xa, r0 + 1, w, le, re);
    Raw nB = load_row(xb, r0 + 1, w, le, re);

    float4 psA, pqA, csA, cqA, psB, pqB, csB, cqB;
    row_sums(pA, psA, pqA);
    row_sums(pB, psB, pqB);
    row_sums(cA, csA, cqA);
    row_sums(cB, csB, cqB);

    // Invariant at iter h: ps*=sums(h-1), cs*=sums(h), n*=raw(h+1).
    #pragma unroll 2
    for (int h = r0; h < r1 - 1; ++h) {
        int h2 = h + 2;
        if (h2 > H - 1) h2 = H - 2;   // reflect (last chunk only)
        // Issue next-next loads for BOTH streams before consuming n*.
        Raw mA = load_row(xa, h2, w, le, re);
        Raw mB = load_row(xb, h2, w, le, re);

        float4 nsA, nqA, nsB, nqB;
        row_sums(nA, nsA, nqA);
        row_sums(nB, nsB, nqB);
        emit_row(oa, h, psA, csA, nsA, pqA, cqA, nqA);
        emit_row(ob, h, psB, csB, nsB, pqB, cqB, nqB);

        psA = csA; pqA = cqA; csA = nsA; cqA = nqA;
        psB = csB; pqB = cqB; csB = nsB; cqB = nqB;
        nA = mA; nB = mB;
    }

    // Epilogue: emit row r1-1 (n* holds raw(r1) or its reflection).
    float4 nsA, nqA, nsB, nqB;
    row_sums(nA, nsA, nqA);
    row_sums(nB, nsB, nqB);
    emit_row(oa, r1 - 1, psA, csA, nsA, pqA, cqA, nqA);
    emit_row(ob, r1 - 1, psB, csB, nsB, pqB, cqB, nqB);
}

extern "C" void kernel_launch(void* const* d_in, const int* in_sizes, int n_in,
                              void* d_out, int out_size, void* d_ws, size_t ws_size,
                              hipStream_t stream) {
    const float* x = (const float*)d_in[0];
    float* out = (float*)d_out;
    (void)in_sizes; (void)n_in; (void)out_size; (void)d_ws; (void)ws_size;

    const int total_threads = NP_PH * NP_CHUNKS * NP_STRIPS;  // 688128
    const int block = 256;
    const int grid = total_threads / block;  // 2688
    NormPool2d_kernel<<<grid, block, 0, stream>>>(x, out);
}